// Round 3
// baseline (2103.983 us; speedup 1.0000x reference)
//
#include <hip/hip_runtime.h>
#include <hip/hip_bf16.h>
#include <math.h>

#define F_IN 512
#define H1   16
#define C2   40
#define BK   256   // nodes per bucket (dst >> 8)

__device__ __forceinline__ float bf2f(unsigned short u) {
  union { unsigned int i; float f; } v; v.i = ((unsigned int)u) << 16; return v.f;
}
__device__ __forceinline__ unsigned short f2bf(float f) {
  __hip_bfloat16 b = __float2bfloat16(f);  // RNE
  return *reinterpret_cast<unsigned short*>(&b);
}

// ---------------- zero degree ----------------
__global__ __launch_bounds__(256) void k_zero(int* deg, int n) {
  int i = blockIdx.x * 256 + threadIdx.x;
  if (i < n) deg[i] = 0;
}

// ---------------- in-degree histogram (int atomics) ----------------
__global__ __launch_bounds__(256) void k_degree(const int* __restrict__ dst, int* deg, int E) {
  int stride = gridDim.x * 256;
  for (int e = blockIdx.x * 256 + threadIdx.x; e < E; e += stride)
    atomicAdd(&deg[dst[e]], 1);
}

// ---------------- dinv = rsqrt(deg + 1 self-loop) ----------------
__global__ __launch_bounds__(256) void k_dinv(const int* __restrict__ deg, float* dinv, int N) {
  int i = blockIdx.x * 256 + threadIdx.x;
  if (i < N) dinv[i] = rsqrtf((float)(deg[i] + 1));
}

// ---------------- bucket sizes + exclusive scan + cursor init (1 block) ----------------
__global__ __launch_bounds__(512) void k_bscan(const int* __restrict__ deg,
                                               int* bstart, int* bcur,
                                               int N, int E, int NB) {
  __shared__ int lds[512];
  int t = threadIdx.x;
  int s = 0;
  if (t < NB) {
    int base = t * BK;
#pragma unroll 4
    for (int i = 0; i < BK; i++) {
      int n = base + i;
      if (n < N) s += deg[n];
    }
  }
  lds[t] = s;
  __syncthreads();
  for (int off = 1; off < 512; off <<= 1) {
    int add = (t >= off) ? lds[t - off] : 0;
    __syncthreads();
    lds[t] += add;
    __syncthreads();
  }
  if (t < NB) {
    int excl = lds[t] - s;
    bstart[t] = excl;
    bcur[t]  = excl;
  }
  if (t == 0) bstart[NB] = E;
}

// ---------------- bucket fill: ebuf[pos] = (src<<8) | (dst&255) ----------------
// Writes confined to ~NB frontier cache lines -> lines fill completely, HBM
// write ~= payload (12.8 MB) instead of 64B per 4B store.
__global__ __launch_bounds__(256) void k_fill(const int* __restrict__ src,
                                              const int* __restrict__ dst,
                                              int* bcur, unsigned* __restrict__ ebuf, int E) {
  int stride = gridDim.x * 256;
  for (int e = blockIdx.x * 256 + threadIdx.x; e < E; e += stride) {
    int d = dst[e];
    int pos = atomicAdd(&bcur[d >> 8], 1);
    ebuf[pos] = ((unsigned)src[e] << 8) | (unsigned)(d & 255);
  }
}

// ---------------- g1 = bf16( (x @ W1) * dinv[row] ) ----------------
// One wave per row (grid-stride), software-pipelined row loads. Lane l holds
// W1[8l..8l+8)[:] in 128 regs; 128 FMAs/row; 6-step reduce-scatter butterfly.
__global__ __launch_bounds__(256, 2) void k_gemm1(const float* __restrict__ x,
                                                  const float* __restrict__ W1,
                                                  const float* __restrict__ dinv,
                                                  unsigned short* __restrict__ g1bf, int N) {
  int lane = threadIdx.x & 63;
  int wid = (int)((blockIdx.x * (long long)blockDim.x + threadIdx.x) >> 6);
  int nw = (gridDim.x * blockDim.x) >> 6;

  float wr[128];
#pragma unroll
  for (int j = 0; j < 8; j++) {
    const float* wrow = &W1[(lane * 8 + j) * H1];
    float4 w0 = *(const float4*)&wrow[0];
    float4 w1 = *(const float4*)&wrow[4];
    float4 w2 = *(const float4*)&wrow[8];
    float4 w3 = *(const float4*)&wrow[12];
    wr[j*16+ 0]=w0.x; wr[j*16+ 1]=w0.y; wr[j*16+ 2]=w0.z; wr[j*16+ 3]=w0.w;
    wr[j*16+ 4]=w1.x; wr[j*16+ 5]=w1.y; wr[j*16+ 6]=w1.z; wr[j*16+ 7]=w1.w;
    wr[j*16+ 8]=w2.x; wr[j*16+ 9]=w2.y; wr[j*16+10]=w2.z; wr[j*16+11]=w2.w;
    wr[j*16+12]=w3.x; wr[j*16+13]=w3.y; wr[j*16+14]=w3.z; wr[j*16+15]=w3.w;
  }

  int row = wid;
  float4 a = make_float4(0,0,0,0), b = make_float4(0,0,0,0);
  if (row < N) {
    const float4* xr = (const float4*)(x + (size_t)row * F_IN);
    a = xr[lane * 2];
    b = xr[lane * 2 + 1];
  }
  while (row < N) {
    int nrow = row + nw;
    float4 na = make_float4(0,0,0,0), nb = make_float4(0,0,0,0);
    if (nrow < N) {
      const float4* xr = (const float4*)(x + (size_t)nrow * F_IN);
      na = xr[lane * 2];
      nb = xr[lane * 2 + 1];
    }
    float xv[8] = {a.x, a.y, a.z, a.w, b.x, b.y, b.z, b.w};
    float acc[16];
#pragma unroll
    for (int c = 0; c < 16; c++) acc[c] = 0.f;
#pragma unroll
    for (int j = 0; j < 8; j++)
#pragma unroll
      for (int c = 0; c < 16; c++) acc[c] = fmaf(xv[j], wr[j * 16 + c], acc[c]);

    float v8[8];
#pragma unroll
    for (int i = 0; i < 8; i++) {
      float t0 = acc[2*i]   + __shfl_xor(acc[2*i],   1, 64);
      float t1 = acc[2*i+1] + __shfl_xor(acc[2*i+1], 1, 64);
      v8[i] = (lane & 1) ? t1 : t0;
    }
    float v4[4];
#pragma unroll
    for (int i = 0; i < 4; i++) {
      float t0 = v8[2*i]   + __shfl_xor(v8[2*i],   2, 64);
      float t1 = v8[2*i+1] + __shfl_xor(v8[2*i+1], 2, 64);
      v4[i] = ((lane >> 1) & 1) ? t1 : t0;
    }
    float v2[2];
#pragma unroll
    for (int i = 0; i < 2; i++) {
      float t0 = v4[2*i]   + __shfl_xor(v4[2*i],   4, 64);
      float t1 = v4[2*i+1] + __shfl_xor(v4[2*i+1], 4, 64);
      v2[i] = ((lane >> 2) & 1) ? t1 : t0;
    }
    float t0 = v2[0] + __shfl_xor(v2[0], 8, 64);
    float t1 = v2[1] + __shfl_xor(v2[1], 8, 64);
    float v1 = ((lane >> 3) & 1) ? t1 : t0;
    v1 += __shfl_xor(v1, 16, 64);
    v1 += __shfl_xor(v1, 32, 64);

    if (lane < 16) g1bf[row * H1 + lane] = f2bf(v1 * dinv[row]);
    row = nrow; a = na; b = nb;
  }
}

// ---------------- layer-1 aggregate (bucket block, LDS acc) + relu epilogue ----------------
__global__ __launch_bounds__(512) void k_agg1(const unsigned* __restrict__ ebuf,
                                              const int* __restrict__ bstart,
                                              const unsigned short* __restrict__ g1bf,
                                              const float* __restrict__ dinv,
                                              const float* __restrict__ b1,
                                              unsigned short* __restrict__ g2bf, int N) {
  __shared__ float acc[BK * H1];  // 16 KB
  int t = threadIdx.x;
  int bb = blockIdx.x;
  for (int i = t; i < BK * H1; i += 512) acc[i] = 0.f;
  __syncthreads();

  int e0 = bstart[bb], e1 = bstart[bb + 1];
  int grp = t >> 4, j = t & 15;  // 32 edge-groups of 16 lanes
  for (int base = e0 + grp; base < e1; base += 32 * 4) {
    unsigned p[4]; float v[4];
#pragma unroll
    for (int u = 0; u < 4; u++) {
      int e = base + 32 * u;
      p[u] = (e < e1) ? ebuf[e] : 0u;
    }
#pragma unroll
    for (int u = 0; u < 4; u++) {
      int e = base + 32 * u;
      v[u] = (e < e1) ? bf2f(g1bf[(p[u] >> 8) * H1 + j]) : 0.f;
    }
#pragma unroll
    for (int u = 0; u < 4; u++) {
      int e = base + 32 * u;
      if (e < e1) atomicAdd(&acc[(p[u] & 255) * H1 + j], v[u]);
    }
  }
  __syncthreads();

  if (t < BK) {
    int node = bb * BK + t;
    if (node < N) {
      float di = dinv[node];
      unsigned* dst32 = (unsigned*)g2bf + node * (H1 / 2);
#pragma unroll
      for (int jj = 0; jj < H1; jj += 2) {
        float v0 = di * (acc[t * H1 + jj]     + bf2f(g1bf[node * H1 + jj]))     + b1[jj];
        float v1 = di * (acc[t * H1 + jj + 1] + bf2f(g1bf[node * H1 + jj + 1])) + b1[jj + 1];
        v0 = fmaxf(v0, 0.f) * di;
        v1 = fmaxf(v1, 0.f) * di;
        dst32[jj >> 1] = (unsigned)f2bf(v0) | ((unsigned)f2bf(v1) << 16);
      }
    }
  }
}

// ---------------- layer-2 aggregate + W2 + bias + log_softmax ----------------
__global__ __launch_bounds__(512) void k_agg2(const unsigned* __restrict__ ebuf,
                                              const int* __restrict__ bstart,
                                              const unsigned short* __restrict__ g2bf,
                                              const float* __restrict__ dinv,
                                              const float* __restrict__ W2,
                                              const float* __restrict__ b2,
                                              float* __restrict__ out, int N) {
  __shared__ float acc[BK * H1];  // 16 KB
  __shared__ float w2s[H1 * C2];
  __shared__ float b2s[C2];
  int t = threadIdx.x;
  int bb = blockIdx.x;
  for (int i = t; i < BK * H1; i += 512) acc[i] = 0.f;
  for (int i = t; i < H1 * C2; i += 512) w2s[i] = W2[i];
  if (t < C2) b2s[t] = b2[t];
  __syncthreads();

  int e0 = bstart[bb], e1 = bstart[bb + 1];
  int grp = t >> 4, j = t & 15;
  for (int base = e0 + grp; base < e1; base += 32 * 4) {
    unsigned p[4]; float v[4];
#pragma unroll
    for (int u = 0; u < 4; u++) {
      int e = base + 32 * u;
      p[u] = (e < e1) ? ebuf[e] : 0u;
    }
#pragma unroll
    for (int u = 0; u < 4; u++) {
      int e = base + 32 * u;
      v[u] = (e < e1) ? bf2f(g2bf[(p[u] >> 8) * H1 + j]) : 0.f;
    }
#pragma unroll
    for (int u = 0; u < 4; u++) {
      int e = base + 32 * u;
      if (e < e1) atomicAdd(&acc[(p[u] & 255) * H1 + j], v[u]);
    }
  }
  __syncthreads();

  int lane = t & 63, w = t >> 6;  // 8 waves x 32 nodes each
  for (int it = 0; it < BK / 8; ++it) {
    int ln = w * 32 + it;
    int node = bb * BK + ln;
    if (node >= N) continue;  // wave-uniform
    float di = dinv[node];
    float s2 = 0.f;
    if (lane < H1) s2 = di * (acc[ln * H1 + lane] + bf2f(g2bf[node * H1 + lane]));
    int cl = (lane < C2) ? lane : 0;
    float z = b2s[cl];
#pragma unroll
    for (int jj = 0; jj < H1; jj++) {
      float sj = __shfl(s2, jj, 64);
      z = fmaf(sj, w2s[jj * C2 + cl], z);
    }
    if (lane >= C2) z = -INFINITY;
    float m = z;
#pragma unroll
    for (int off = 32; off; off >>= 1) m = fmaxf(m, __shfl_xor(m, off, 64));
    float p = (lane < C2) ? expf(z - m) : 0.f;
    float ssum = p;
#pragma unroll
    for (int off = 32; off; off >>= 1) ssum += __shfl_xor(ssum, off, 64);
    if (lane < C2) out[(size_t)node * C2 + lane] = z - m - logf(ssum);
  }
}

extern "C" void kernel_launch(void* const* d_in, const int* in_sizes, int n_in,
                              void* d_out, int out_size, void* d_ws, size_t ws_size,
                              hipStream_t stream) {
  const float* x  = (const float*)d_in[0];
  const int*   ei = (const int*)d_in[1];
  const float* W1 = (const float*)d_in[2];
  const float* b1 = (const float*)d_in[3];
  const float* W2 = (const float*)d_in[4];
  const float* b2 = (const float*)d_in[5];
  float* out = (float*)d_out;

  int N = in_sizes[0] / F_IN;
  int E = in_sizes[1] / 2;
  const int* src = ei;
  const int* dst = ei + E;
  int NB = (N + BK - 1) / BK;  // 391 for N=100000 (must be <= 512)

  char* w = (char*)d_ws;
  size_t off = 0;
  auto alloc = [&](size_t bytes) { char* p = w + off; off = (off + bytes + 255) & ~(size_t)255; return p; };
  int*   deg    = (int*)alloc((size_t)N * 4);
  float* dinv   = (float*)alloc((size_t)N * 4);
  int*   bstart = (int*)alloc((size_t)(NB + 1) * 4);
  int*   bcur   = (int*)alloc((size_t)NB * 4);
  unsigned* ebuf = (unsigned*)alloc((size_t)E * 4);
  unsigned short* g1bf = (unsigned short*)alloc((size_t)N * H1 * 2);
  unsigned short* g2bf = (unsigned short*)alloc((size_t)N * H1 * 2);

  k_zero  <<<(N + 255) / 256, 256, 0, stream>>>(deg, N);
  k_degree<<<4096, 256, 0, stream>>>(dst, deg, E);
  k_dinv  <<<(N + 255) / 256, 256, 0, stream>>>(deg, dinv, N);
  k_bscan <<<1, 512, 0, stream>>>(deg, bstart, bcur, N, E, NB);
  k_fill  <<<4096, 256, 0, stream>>>(src, dst, bcur, ebuf, E);
  k_gemm1 <<<1024, 256, 0, stream>>>(x, W1, dinv, g1bf, N);
  k_agg1  <<<NB, 512, 0, stream>>>(ebuf, bstart, g1bf, dinv, b1, g2bf, N);
  k_agg2  <<<NB, 512, 0, stream>>>(ebuf, bstart, g2bf, dinv, W2, b2, out, N);
}

// Round 4
// 886.671 us; speedup vs baseline: 2.3729x; 2.3729x over previous
//
#include <hip/hip_runtime.h>
#include <hip/hip_bf16.h>
#include <math.h>

#define F_IN 512
#define H1   16
#define C2   40
#define BK   256   // nodes per bucket (dst >> 8)
#define NBMAX 512
#define G    256   // edge-chunk groups for count/fill

__device__ __forceinline__ float bf2f(unsigned short u) {
  union { unsigned int i; float f; } v; v.i = ((unsigned int)u) << 16; return v.f;
}
__device__ __forceinline__ unsigned short f2bf(float f) {
  __hip_bfloat16 b = __float2bfloat16(f);  // RNE
  return *reinterpret_cast<unsigned short*>(&b);
}

// ---------------- phase 1: per-chunk bucket histogram (LDS atomics only) ----------------
__global__ __launch_bounds__(256) void k_count(const int* __restrict__ dst,
                                               int* __restrict__ cnt,
                                               int E, int NB, int epb) {
  __shared__ int h[NBMAX];
  int g = blockIdx.x, t = threadIdx.x;
  for (int i = t; i < NB; i += 256) h[i] = 0;
  __syncthreads();
  int e0 = g * epb, e1 = min(e0 + epb, E);
  for (int e = e0 + t; e < e1; e += 256) atomicAdd(&h[dst[e] >> 8], 1);
  __syncthreads();
  for (int i = t; i < NB; i += 256) cnt[g * NB + i] = h[i];
}

// ---------------- phase 2a: per-bucket exclusive scan over the G groups ----------------
__global__ __launch_bounds__(G) void k_scan_col(int* cnt, int* tot, int NB) {
  __shared__ int lds[G];
  int b = blockIdx.x, t = threadIdx.x;
  int v = cnt[t * NB + b];
  lds[t] = v;
  __syncthreads();
  for (int off = 1; off < G; off <<= 1) {
    int add = (t >= off) ? lds[t - off] : 0;
    __syncthreads();
    lds[t] += add;
    __syncthreads();
  }
  cnt[t * NB + b] = lds[t] - v;         // exclusive within bucket
  if (t == G - 1) tot[b] = lds[G - 1];  // bucket total
}

// ---------------- phase 2b: exclusive scan of bucket totals ----------------
__global__ __launch_bounds__(512) void k_scan_tot(const int* __restrict__ tot,
                                                  int* bstart, int NB, int E) {
  __shared__ int lds[512];
  int t = threadIdx.x;
  int v = (t < NB) ? tot[t] : 0;
  lds[t] = v;
  __syncthreads();
  for (int off = 1; off < 512; off <<= 1) {
    int add = (t >= off) ? lds[t - off] : 0;
    __syncthreads();
    lds[t] += add;
    __syncthreads();
  }
  if (t < NB) bstart[t] = lds[t] - v;
  if (t == 0) bstart[NB] = E;
}

// ---------------- phase 3: fill (LDS cursors, private sub-ranges, no global atomics) ----------------
__global__ __launch_bounds__(256) void k_fill(const int* __restrict__ src,
                                              const int* __restrict__ dst,
                                              const int* __restrict__ cnt,
                                              const int* __restrict__ bstart,
                                              unsigned* __restrict__ ebuf,
                                              int E, int NB, int epb) {
  __shared__ int cur[NBMAX];
  int g = blockIdx.x, t = threadIdx.x;
  for (int i = t; i < NB; i += 256) cur[i] = bstart[i] + cnt[g * NB + i];
  __syncthreads();
  int e0 = g * epb, e1 = min(e0 + epb, E);
  for (int e = e0 + t; e < e1; e += 256) {
    int d = dst[e];
    int pos = atomicAdd(&cur[d >> 8], 1);
    ebuf[pos] = ((unsigned)src[e] << 8) | (unsigned)(d & 255);
  }
}

// ---------------- per-node degree from grouped ebuf -> dinv ----------------
__global__ __launch_bounds__(256) void k_dinv2(const unsigned* __restrict__ ebuf,
                                               const int* __restrict__ bstart,
                                               float* __restrict__ dinv, int N) {
  __shared__ int c[BK];
  int b = blockIdx.x, t = threadIdx.x;
  c[t] = 0;
  __syncthreads();
  int e0 = bstart[b], e1 = bstart[b + 1];
  for (int e = e0 + t; e < e1; e += 256) atomicAdd(&c[ebuf[e] & 255], 1);
  __syncthreads();
  int node = b * BK + t;
  if (node < N) dinv[node] = rsqrtf((float)(c[t] + 1));
}

// ---------------- g1 = bf16( x @ W1 )  (unscaled; dinv applied at gather) ----------------
__global__ __launch_bounds__(256, 2) void k_gemm1(const float* __restrict__ x,
                                                  const float* __restrict__ W1,
                                                  unsigned short* __restrict__ g1bf, int N) {
  int lane = threadIdx.x & 63;
  int wid = (int)((blockIdx.x * (long long)blockDim.x + threadIdx.x) >> 6);
  int nw = (gridDim.x * blockDim.x) >> 6;

  float wr[128];
#pragma unroll
  for (int j = 0; j < 8; j++) {
    const float* wrow = &W1[(lane * 8 + j) * H1];
    float4 w0 = *(const float4*)&wrow[0];
    float4 w1 = *(const float4*)&wrow[4];
    float4 w2 = *(const float4*)&wrow[8];
    float4 w3 = *(const float4*)&wrow[12];
    wr[j*16+ 0]=w0.x; wr[j*16+ 1]=w0.y; wr[j*16+ 2]=w0.z; wr[j*16+ 3]=w0.w;
    wr[j*16+ 4]=w1.x; wr[j*16+ 5]=w1.y; wr[j*16+ 6]=w1.z; wr[j*16+ 7]=w1.w;
    wr[j*16+ 8]=w2.x; wr[j*16+ 9]=w2.y; wr[j*16+10]=w2.z; wr[j*16+11]=w2.w;
    wr[j*16+12]=w3.x; wr[j*16+13]=w3.y; wr[j*16+14]=w3.z; wr[j*16+15]=w3.w;
  }

  int row = wid;
  float4 a = make_float4(0,0,0,0), b = make_float4(0,0,0,0);
  if (row < N) {
    const float4* xr = (const float4*)(x + (size_t)row * F_IN);
    a = xr[lane * 2];
    b = xr[lane * 2 + 1];
  }
  while (row < N) {
    int nrow = row + nw;
    float4 na = make_float4(0,0,0,0), nb = make_float4(0,0,0,0);
    if (nrow < N) {
      const float4* xr = (const float4*)(x + (size_t)nrow * F_IN);
      na = xr[lane * 2];
      nb = xr[lane * 2 + 1];
    }
    float xv[8] = {a.x, a.y, a.z, a.w, b.x, b.y, b.z, b.w};
    float acc[16];
#pragma unroll
    for (int c = 0; c < 16; c++) acc[c] = 0.f;
#pragma unroll
    for (int j = 0; j < 8; j++)
#pragma unroll
      for (int c = 0; c < 16; c++) acc[c] = fmaf(xv[j], wr[j * 16 + c], acc[c]);

    float v8[8];
#pragma unroll
    for (int i = 0; i < 8; i++) {
      float t0 = acc[2*i]   + __shfl_xor(acc[2*i],   1, 64);
      float t1 = acc[2*i+1] + __shfl_xor(acc[2*i+1], 1, 64);
      v8[i] = (lane & 1) ? t1 : t0;
    }
    float v4[4];
#pragma unroll
    for (int i = 0; i < 4; i++) {
      float t0 = v8[2*i]   + __shfl_xor(v8[2*i],   2, 64);
      float t1 = v8[2*i+1] + __shfl_xor(v8[2*i+1], 2, 64);
      v4[i] = ((lane >> 1) & 1) ? t1 : t0;
    }
    float v2[2];
#pragma unroll
    for (int i = 0; i < 2; i++) {
      float t0 = v4[2*i]   + __shfl_xor(v4[2*i],   4, 64);
      float t1 = v4[2*i+1] + __shfl_xor(v4[2*i+1], 4, 64);
      v2[i] = ((lane >> 2) & 1) ? t1 : t0;
    }
    float t0 = v2[0] + __shfl_xor(v2[0], 8, 64);
    float t1 = v2[1] + __shfl_xor(v2[1], 8, 64);
    float v1 = ((lane >> 3) & 1) ? t1 : t0;
    v1 += __shfl_xor(v1, 16, 64);
    v1 += __shfl_xor(v1, 32, 64);

    if (lane < 16) g1bf[row * H1 + lane] = f2bf(v1);
    row = nrow; a = na; b = nb;
  }
}

// ---------------- layer-1 aggregate (bucket block, LDS acc) + relu epilogue ----------------
__global__ __launch_bounds__(512) void k_agg1(const unsigned* __restrict__ ebuf,
                                              const int* __restrict__ bstart,
                                              const unsigned short* __restrict__ g1bf,
                                              const float* __restrict__ dinv,
                                              const float* __restrict__ b1,
                                              unsigned short* __restrict__ g2bf, int N) {
  __shared__ float acc[BK * H1];  // 16 KB
  int t = threadIdx.x;
  int bb = blockIdx.x;
  for (int i = t; i < BK * H1; i += 512) acc[i] = 0.f;
  __syncthreads();

  int e0 = bstart[bb], e1 = bstart[bb + 1];
  int grp = t >> 4, j = t & 15;  // 32 edge-groups of 16 lanes
  for (int base = e0 + grp; base < e1; base += 32 * 4) {
    unsigned p[4]; float v[4];
#pragma unroll
    for (int u = 0; u < 4; u++) {
      int e = base + 32 * u;
      p[u] = (e < e1) ? ebuf[e] : 0u;
    }
#pragma unroll
    for (int u = 0; u < 4; u++) {
      int e = base + 32 * u;
      v[u] = (e < e1) ? bf2f(g1bf[(p[u] >> 8) * H1 + j]) * dinv[p[u] >> 8] : 0.f;
    }
#pragma unroll
    for (int u = 0; u < 4; u++) {
      int e = base + 32 * u;
      if (e < e1) atomicAdd(&acc[(p[u] & 255) * H1 + j], v[u]);
    }
  }
  __syncthreads();

  if (t < BK) {
    int node = bb * BK + t;
    if (node < N) {
      float di = dinv[node];
      unsigned* dst32 = (unsigned*)g2bf + node * (H1 / 2);
#pragma unroll
      for (int jj = 0; jj < H1; jj += 2) {
        float v0 = di * (acc[t * H1 + jj]     + di * bf2f(g1bf[node * H1 + jj]))     + b1[jj];
        float v1 = di * (acc[t * H1 + jj + 1] + di * bf2f(g1bf[node * H1 + jj + 1])) + b1[jj + 1];
        v0 = fmaxf(v0, 0.f) * di;
        v1 = fmaxf(v1, 0.f) * di;
        dst32[jj >> 1] = (unsigned)f2bf(v0) | ((unsigned)f2bf(v1) << 16);
      }
    }
  }
}

// ---------------- layer-2 aggregate + W2 + bias + log_softmax ----------------
__global__ __launch_bounds__(512) void k_agg2(const unsigned* __restrict__ ebuf,
                                              const int* __restrict__ bstart,
                                              const unsigned short* __restrict__ g2bf,
                                              const float* __restrict__ dinv,
                                              const float* __restrict__ W2,
                                              const float* __restrict__ b2,
                                              float* __restrict__ out, int N) {
  __shared__ float acc[BK * H1];  // 16 KB
  __shared__ float w2s[H1 * C2];
  __shared__ float b2s[C2];
  int t = threadIdx.x;
  int bb = blockIdx.x;
  for (int i = t; i < BK * H1; i += 512) acc[i] = 0.f;
  for (int i = t; i < H1 * C2; i += 512) w2s[i] = W2[i];
  if (t < C2) b2s[t] = b2[t];
  __syncthreads();

  int e0 = bstart[bb], e1 = bstart[bb + 1];
  int grp = t >> 4, j = t & 15;
  for (int base = e0 + grp; base < e1; base += 32 * 4) {
    unsigned p[4]; float v[4];
#pragma unroll
    for (int u = 0; u < 4; u++) {
      int e = base + 32 * u;
      p[u] = (e < e1) ? ebuf[e] : 0u;
    }
#pragma unroll
    for (int u = 0; u < 4; u++) {
      int e = base + 32 * u;
      v[u] = (e < e1) ? bf2f(g2bf[(p[u] >> 8) * H1 + j]) : 0.f;
    }
#pragma unroll
    for (int u = 0; u < 4; u++) {
      int e = base + 32 * u;
      if (e < e1) atomicAdd(&acc[(p[u] & 255) * H1 + j], v[u]);
    }
  }
  __syncthreads();

  int lane = t & 63, w = t >> 6;  // 8 waves x 32 nodes each
  for (int it = 0; it < BK / 8; ++it) {
    int ln = w * 32 + it;
    int node = bb * BK + ln;
    if (node >= N) continue;  // wave-uniform
    float di = dinv[node];
    float s2 = 0.f;
    if (lane < H1) s2 = di * (acc[ln * H1 + lane] + bf2f(g2bf[node * H1 + lane]));
    int cl = (lane < C2) ? lane : 0;
    float z = b2s[cl];
#pragma unroll
    for (int jj = 0; jj < H1; jj++) {
      float sj = __shfl(s2, jj, 64);
      z = fmaf(sj, w2s[jj * C2 + cl], z);
    }
    if (lane >= C2) z = -INFINITY;
    float m = z;
#pragma unroll
    for (int off = 32; off; off >>= 1) m = fmaxf(m, __shfl_xor(m, off, 64));
    float p = (lane < C2) ? expf(z - m) : 0.f;
    float ssum = p;
#pragma unroll
    for (int off = 32; off; off >>= 1) ssum += __shfl_xor(ssum, off, 64);
    if (lane < C2) out[(size_t)node * C2 + lane] = z - m - logf(ssum);
  }
}

extern "C" void kernel_launch(void* const* d_in, const int* in_sizes, int n_in,
                              void* d_out, int out_size, void* d_ws, size_t ws_size,
                              hipStream_t stream) {
  const float* x  = (const float*)d_in[0];
  const int*   ei = (const int*)d_in[1];
  const float* W1 = (const float*)d_in[2];
  const float* b1 = (const float*)d_in[3];
  const float* W2 = (const float*)d_in[4];
  const float* b2 = (const float*)d_in[5];
  float* out = (float*)d_out;

  int N = in_sizes[0] / F_IN;
  int E = in_sizes[1] / 2;
  const int* src = ei;
  const int* dst = ei + E;
  int NB = (N + BK - 1) / BK;     // 391 for N=100000 (must be <= NBMAX)
  int epb = (E + G - 1) / G;      // edges per chunk group

  char* w = (char*)d_ws;
  size_t off = 0;
  auto alloc = [&](size_t bytes) { char* p = w + off; off = (off + bytes + 255) & ~(size_t)255; return p; };
  int*   cnt    = (int*)alloc((size_t)G * NB * 4);
  int*   tot    = (int*)alloc((size_t)NB * 4);
  int*   bstart = (int*)alloc((size_t)(NB + 1) * 4);
  float* dinv   = (float*)alloc((size_t)N * 4);
  unsigned* ebuf = (unsigned*)alloc((size_t)E * 4);
  unsigned short* g1bf = (unsigned short*)alloc((size_t)N * H1 * 2);
  unsigned short* g2bf = (unsigned short*)alloc((size_t)N * H1 * 2);

  k_count   <<<G, 256, 0, stream>>>(dst, cnt, E, NB, epb);
  k_scan_col<<<NB, G, 0, stream>>>(cnt, tot, NB);
  k_scan_tot<<<1, 512, 0, stream>>>(tot, bstart, NB, E);
  k_fill    <<<G, 256, 0, stream>>>(src, dst, cnt, bstart, ebuf, E, NB, epb);
  k_dinv2   <<<NB, 256, 0, stream>>>(ebuf, bstart, dinv, N);
  k_gemm1   <<<1024, 256, 0, stream>>>(x, W1, g1bf, N);
  k_agg1    <<<NB, 512, 0, stream>>>(ebuf, bstart, g1bf, dinv, b1, g2bf, N);
  k_agg2    <<<NB, 512, 0, stream>>>(ebuf, bstart, g2bf, dinv, W2, b2, out, N);
}

// Round 5
// 832.822 us; speedup vs baseline: 2.5263x; 1.0647x over previous
//
#include <hip/hip_runtime.h>
#include <hip/hip_bf16.h>
#include <math.h>

#define F_IN 512
#define H1   16
#define C2   40
#define BKL  6                 // log2(nodes per bucket)
#define BK   (1 << BKL)        // 64 nodes per bucket
#define NBMAX 2048
#define G    256               // edge-chunk groups for count/fill

__device__ __forceinline__ float bf2f(unsigned short u) {
  union { unsigned int i; float f; } v; v.i = ((unsigned int)u) << 16; return v.f;
}
__device__ __forceinline__ unsigned short f2bf(float f) {
  __hip_bfloat16 b = __float2bfloat16(f);  // RNE
  return *reinterpret_cast<unsigned short*>(&b);
}

// ---------------- phase 1: per-chunk bucket histogram (LDS atomics only) ----------------
__global__ __launch_bounds__(256) void k_count(const int* __restrict__ dst,
                                               int* __restrict__ cnt,
                                               int E, int NB, int epb) {
  __shared__ int h[NBMAX];
  int g = blockIdx.x, t = threadIdx.x;
  for (int i = t; i < NB; i += 256) h[i] = 0;
  __syncthreads();
  int e0 = g * epb, e1 = min(e0 + epb, E);
  for (int e = e0 + t; e < e1; e += 256) atomicAdd(&h[dst[e] >> BKL], 1);
  __syncthreads();
  for (int i = t; i < NB; i += 256) cnt[g * NB + i] = h[i];
}

// ---------------- phase 2a: per-bucket exclusive scan over the G groups ----------------
__global__ __launch_bounds__(G) void k_scan_col(int* cnt, int* tot, int NB) {
  __shared__ int lds[G];
  int b = blockIdx.x, t = threadIdx.x;
  int v = cnt[t * NB + b];
  lds[t] = v;
  __syncthreads();
  for (int off = 1; off < G; off <<= 1) {
    int add = (t >= off) ? lds[t - off] : 0;
    __syncthreads();
    lds[t] += add;
    __syncthreads();
  }
  cnt[t * NB + b] = lds[t] - v;         // exclusive within bucket
  if (t == G - 1) tot[b] = lds[G - 1];  // bucket total
}

// ---------------- phase 2b: exclusive scan of bucket totals (NB <= 2048) ----------------
__global__ __launch_bounds__(512) void k_scan_tot(const int* __restrict__ tot,
                                                  int* bstart, int NB, int E) {
  __shared__ int lds[512];
  int t = threadIdx.x;
  int b0 = t * 4;
  int v[4];
  int s = 0;
#pragma unroll
  for (int k = 0; k < 4; k++) { v[k] = (b0 + k < NB) ? tot[b0 + k] : 0; s += v[k]; }
  lds[t] = s;
  __syncthreads();
  for (int off = 1; off < 512; off <<= 1) {
    int add = (t >= off) ? lds[t - off] : 0;
    __syncthreads();
    lds[t] += add;
    __syncthreads();
  }
  int excl = lds[t] - s;
#pragma unroll
  for (int k = 0; k < 4; k++) {
    if (b0 + k < NB) bstart[b0 + k] = excl;
    excl += v[k];
  }
  if (t == 0) bstart[NB] = E;
}

// ---------------- phase 3: fill (LDS cursors, private sub-ranges, no global atomics) ----------------
__global__ __launch_bounds__(256) void k_fill(const int* __restrict__ src,
                                              const int* __restrict__ dst,
                                              const int* __restrict__ cnt,
                                              const int* __restrict__ bstart,
                                              unsigned* __restrict__ ebuf,
                                              int E, int NB, int epb) {
  __shared__ int cur[NBMAX];
  int g = blockIdx.x, t = threadIdx.x;
  for (int i = t; i < NB; i += 256) cur[i] = bstart[i] + cnt[g * NB + i];
  __syncthreads();
  int e0 = g * epb, e1 = min(e0 + epb, E);
  for (int e = e0 + t; e < e1; e += 256) {
    int d = dst[e];
    int pos = atomicAdd(&cur[d >> BKL], 1);
    ebuf[pos] = ((unsigned)src[e] << BKL) | (unsigned)(d & (BK - 1));
  }
}

// ---------------- per-node degree from grouped ebuf -> dinv ----------------
__global__ __launch_bounds__(256) void k_dinv2(const unsigned* __restrict__ ebuf,
                                               const int* __restrict__ bstart,
                                               float* __restrict__ dinv, int N) {
  __shared__ int c[BK];
  int b = blockIdx.x, t = threadIdx.x;
  if (t < BK) c[t] = 0;
  __syncthreads();
  int e0 = bstart[b], e1 = bstart[b + 1];
  for (int e = e0 + t; e < e1; e += 256) atomicAdd(&c[ebuf[e] & (BK - 1)], 1);
  __syncthreads();
  int node = b * BK + t;
  if (t < BK && node < N) dinv[node] = rsqrtf((float)(c[t] + 1));
}

// ---------------- g1 = bf16( (x @ W1) * dinv[row] ) ----------------
// One wave per row (grid-stride), software-pipelined row loads. Lane l holds
// W1[8l..8l+8)[:] in 128 regs; 128 FMAs/row; 6-step reduce-scatter butterfly.
__global__ __launch_bounds__(256, 2) void k_gemm1(const float* __restrict__ x,
                                                  const float* __restrict__ W1,
                                                  const float* __restrict__ dinv,
                                                  unsigned short* __restrict__ g1bf, int N) {
  int lane = threadIdx.x & 63;
  int wid = (int)((blockIdx.x * (long long)blockDim.x + threadIdx.x) >> 6);
  int nw = (gridDim.x * blockDim.x) >> 6;

  float wr[128];
#pragma unroll
  for (int j = 0; j < 8; j++) {
    const float* wrow = &W1[(lane * 8 + j) * H1];
    float4 w0 = *(const float4*)&wrow[0];
    float4 w1 = *(const float4*)&wrow[4];
    float4 w2 = *(const float4*)&wrow[8];
    float4 w3 = *(const float4*)&wrow[12];
    wr[j*16+ 0]=w0.x; wr[j*16+ 1]=w0.y; wr[j*16+ 2]=w0.z; wr[j*16+ 3]=w0.w;
    wr[j*16+ 4]=w1.x; wr[j*16+ 5]=w1.y; wr[j*16+ 6]=w1.z; wr[j*16+ 7]=w1.w;
    wr[j*16+ 8]=w2.x; wr[j*16+ 9]=w2.y; wr[j*16+10]=w2.z; wr[j*16+11]=w2.w;
    wr[j*16+12]=w3.x; wr[j*16+13]=w3.y; wr[j*16+14]=w3.z; wr[j*16+15]=w3.w;
  }

  int row = wid;
  float4 a = make_float4(0,0,0,0), b = make_float4(0,0,0,0);
  if (row < N) {
    const float4* xr = (const float4*)(x + (size_t)row * F_IN);
    a = xr[lane * 2];
    b = xr[lane * 2 + 1];
  }
  while (row < N) {
    int nrow = row + nw;
    float4 na = make_float4(0,0,0,0), nb = make_float4(0,0,0,0);
    if (nrow < N) {
      const float4* xr = (const float4*)(x + (size_t)nrow * F_IN);
      na = xr[lane * 2];
      nb = xr[lane * 2 + 1];
    }
    float xv[8] = {a.x, a.y, a.z, a.w, b.x, b.y, b.z, b.w};
    float acc[16];
#pragma unroll
    for (int c = 0; c < 16; c++) acc[c] = 0.f;
#pragma unroll
    for (int j = 0; j < 8; j++)
#pragma unroll
      for (int c = 0; c < 16; c++) acc[c] = fmaf(xv[j], wr[j * 16 + c], acc[c]);

    float v8[8];
#pragma unroll
    for (int i = 0; i < 8; i++) {
      float t0 = acc[2*i]   + __shfl_xor(acc[2*i],   1, 64);
      float t1 = acc[2*i+1] + __shfl_xor(acc[2*i+1], 1, 64);
      v8[i] = (lane & 1) ? t1 : t0;
    }
    float v4[4];
#pragma unroll
    for (int i = 0; i < 4; i++) {
      float t0 = v8[2*i]   + __shfl_xor(v8[2*i],   2, 64);
      float t1 = v8[2*i+1] + __shfl_xor(v8[2*i+1], 2, 64);
      v4[i] = ((lane >> 1) & 1) ? t1 : t0;
    }
    float v2[2];
#pragma unroll
    for (int i = 0; i < 2; i++) {
      float t0 = v4[2*i]   + __shfl_xor(v4[2*i],   4, 64);
      float t1 = v4[2*i+1] + __shfl_xor(v4[2*i+1], 4, 64);
      v2[i] = ((lane >> 2) & 1) ? t1 : t0;
    }
    float t0 = v2[0] + __shfl_xor(v2[0], 8, 64);
    float t1 = v2[1] + __shfl_xor(v2[1], 8, 64);
    float v1 = ((lane >> 3) & 1) ? t1 : t0;
    v1 += __shfl_xor(v1, 16, 64);
    v1 += __shfl_xor(v1, 32, 64);

    if (lane < 16) g1bf[row * H1 + lane] = f2bf(v1 * dinv[row]);
    row = nrow; a = na; b = nb;
  }
}

// ---------------- layer-1 aggregate (64-node bucket, 4KB LDS acc) + relu epilogue ----------------
__global__ __launch_bounds__(256) void k_agg1(const unsigned* __restrict__ ebuf,
                                              const int* __restrict__ bstart,
                                              const unsigned short* __restrict__ g1bf,
                                              const float* __restrict__ dinv,
                                              const float* __restrict__ b1,
                                              unsigned short* __restrict__ g2bf, int N) {
  __shared__ float acc[BK * H1];  // 4 KB
  int t = threadIdx.x;
  int bb = blockIdx.x;
  for (int i = t; i < BK * H1; i += 256) acc[i] = 0.f;
  __syncthreads();

  int e0 = bstart[bb], e1 = bstart[bb + 1];
  int grp = t >> 4, j = t & 15;  // 16 edge-groups of 16 lanes
#define U 8
  for (int base = e0 + grp; base < e1; base += 16 * U) {
    unsigned p[U]; float v[U];
#pragma unroll
    for (int u = 0; u < U; u++) {
      int e = base + 16 * u;
      p[u] = (e < e1) ? ebuf[e] : 0u;
    }
#pragma unroll
    for (int u = 0; u < U; u++) {
      int e = base + 16 * u;
      v[u] = (e < e1) ? bf2f(g1bf[(p[u] >> BKL) * H1 + j]) : 0.f;
    }
#pragma unroll
    for (int u = 0; u < U; u++) {
      int e = base + 16 * u;
      if (e < e1) atomicAdd(&acc[(p[u] & (BK - 1)) * H1 + j], v[u]);
    }
  }
  __syncthreads();

  if (t < BK * 2) {
    int nl = t >> 1, half = (t & 1) * 8;
    int node = bb * BK + nl;
    if (node < N) {
      float di = dinv[node];
      unsigned* dst32 = (unsigned*)g2bf + node * (H1 / 2) + (half >> 1);
#pragma unroll
      for (int k = 0; k < 4; k++) {
        int jj = half + 2 * k;
        float v0 = di * (acc[nl * H1 + jj]     + bf2f(g1bf[node * H1 + jj]))     + b1[jj];
        float v1 = di * (acc[nl * H1 + jj + 1] + bf2f(g1bf[node * H1 + jj + 1])) + b1[jj + 1];
        v0 = fmaxf(v0, 0.f) * di;
        v1 = fmaxf(v1, 0.f) * di;
        dst32[k] = (unsigned)f2bf(v0) | ((unsigned)f2bf(v1) << 16);
      }
    }
  }
}

// ---------------- layer-2 aggregate -> s2 fp32 (epilogue in k_ep2) ----------------
__global__ __launch_bounds__(256) void k_agg2(const unsigned* __restrict__ ebuf,
                                              const int* __restrict__ bstart,
                                              const unsigned short* __restrict__ g2bf,
                                              const float* __restrict__ dinv,
                                              float* __restrict__ s2, int N) {
  __shared__ float acc[BK * H1];  // 4 KB
  int t = threadIdx.x;
  int bb = blockIdx.x;
  for (int i = t; i < BK * H1; i += 256) acc[i] = 0.f;
  __syncthreads();

  int e0 = bstart[bb], e1 = bstart[bb + 1];
  int grp = t >> 4, j = t & 15;
  for (int base = e0 + grp; base < e1; base += 16 * U) {
    unsigned p[U]; float v[U];
#pragma unroll
    for (int u = 0; u < U; u++) {
      int e = base + 16 * u;
      p[u] = (e < e1) ? ebuf[e] : 0u;
    }
#pragma unroll
    for (int u = 0; u < U; u++) {
      int e = base + 16 * u;
      v[u] = (e < e1) ? bf2f(g2bf[(p[u] >> BKL) * H1 + j]) : 0.f;
    }
#pragma unroll
    for (int u = 0; u < U; u++) {
      int e = base + 16 * u;
      if (e < e1) atomicAdd(&acc[(p[u] & (BK - 1)) * H1 + j], v[u]);
    }
  }
  __syncthreads();

  if (t < BK * 2) {
    int nl = t >> 1, half = (t & 1) * 8;
    int node = bb * BK + nl;
    if (node < N) {
      float di = dinv[node];
#pragma unroll
      for (int k = 0; k < 8; k++) {
        int jj = half + k;
        s2[node * H1 + jj] = di * (acc[nl * H1 + jj] + bf2f(g2bf[node * H1 + jj]));
      }
    }
  }
}

// ---------------- final epilogue: out = log_softmax(s2 @ W2 + b2) ----------------
__global__ __launch_bounds__(256) void k_ep2(const float* __restrict__ s2,
                                             const float* __restrict__ W2,
                                             const float* __restrict__ b2,
                                             float* __restrict__ out, int N) {
  __shared__ float w2s[H1 * C2];
  __shared__ float b2s[C2];
  int t = threadIdx.x;
  for (int i = t; i < H1 * C2; i += 256) w2s[i] = W2[i];
  if (t < C2) b2s[t] = b2[t];
  __syncthreads();

  int lane = t & 63;
  int node = (int)((blockIdx.x * (long long)blockDim.x + t) >> 6);
  if (node >= N) return;
  float sv = (lane < H1) ? s2[node * H1 + lane] : 0.f;
  int cl = (lane < C2) ? lane : 0;
  float z = b2s[cl];
#pragma unroll
  for (int jj = 0; jj < H1; jj++) {
    float sj = __shfl(sv, jj, 64);
    z = fmaf(sj, w2s[jj * C2 + cl], z);
  }
  if (lane >= C2) z = -INFINITY;
  float m = z;
#pragma unroll
  for (int off = 32; off; off >>= 1) m = fmaxf(m, __shfl_xor(m, off, 64));
  float p = (lane < C2) ? expf(z - m) : 0.f;
  float ssum = p;
#pragma unroll
  for (int off = 32; off; off >>= 1) ssum += __shfl_xor(ssum, off, 64);
  if (lane < C2) out[(size_t)node * C2 + lane] = z - m - logf(ssum);
}

extern "C" void kernel_launch(void* const* d_in, const int* in_sizes, int n_in,
                              void* d_out, int out_size, void* d_ws, size_t ws_size,
                              hipStream_t stream) {
  const float* x  = (const float*)d_in[0];
  const int*   ei = (const int*)d_in[1];
  const float* W1 = (const float*)d_in[2];
  const float* b1 = (const float*)d_in[3];
  const float* W2 = (const float*)d_in[4];
  const float* b2 = (const float*)d_in[5];
  float* out = (float*)d_out;

  int N = in_sizes[0] / F_IN;
  int E = in_sizes[1] / 2;
  const int* src = ei;
  const int* dst = ei + E;
  int NB = (N + BK - 1) / BK;     // 1563 for N=100000 (must be <= NBMAX)
  int epb = (E + G - 1) / G;      // edges per chunk group

  char* w = (char*)d_ws;
  size_t off = 0;
  auto alloc = [&](size_t bytes) { char* p = w + off; off = (off + bytes + 255) & ~(size_t)255; return p; };
  int*   cnt    = (int*)alloc((size_t)G * NB * 4);
  int*   tot    = (int*)alloc((size_t)NB * 4);
  int*   bstart = (int*)alloc((size_t)(NB + 1) * 4);
  float* dinv   = (float*)alloc((size_t)N * 4);
  unsigned* ebuf = (unsigned*)alloc((size_t)E * 4);
  unsigned short* g1bf = (unsigned short*)alloc((size_t)N * H1 * 2);
  unsigned short* g2bf = (unsigned short*)alloc((size_t)N * H1 * 2);
  float* s2     = (float*)alloc((size_t)N * H1 * 4);

  k_count   <<<G, 256, 0, stream>>>(dst, cnt, E, NB, epb);
  k_scan_col<<<NB, G, 0, stream>>>(cnt, tot, NB);
  k_scan_tot<<<1, 512, 0, stream>>>(tot, bstart, NB, E);
  k_fill    <<<G, 256, 0, stream>>>(src, dst, cnt, bstart, ebuf, E, NB, epb);
  k_dinv2   <<<NB, 256, 0, stream>>>(ebuf, bstart, dinv, N);
  k_gemm1   <<<1024, 256, 0, stream>>>(x, W1, dinv, g1bf, N);
  k_agg1    <<<NB, 256, 0, stream>>>(ebuf, bstart, g1bf, dinv, b1, g2bf, N);
  k_agg2    <<<NB, 256, 0, stream>>>(ebuf, bstart, g2bf, dinv, s2, N);
  k_ep2     <<<(N * 64 + 255) / 256, 256, 0, stream>>>(s2, W2, b2, out, N);
}